// Round 9
// baseline (312.264 us; speedup 1.0000x reference)
//
#include <hip/hip_runtime.h>

#define B_SZ 4096
#define T_SZ 64
#define F_SZ 512
#define H_SZ 64
#define BR 8                    // 512 blocks = 2 blocks/CU
#define WIH_ELEMS (256 * 512)

typedef _Float16 f16x8 __attribute__((ext_vector_type(8)));
typedef float f32x4 __attribute__((ext_vector_type(4)));

__device__ __forceinline__ float fast_rcp(float x) { return __builtin_amdgcn_rcpf(x); }
__device__ __forceinline__ float sigm(float x) { return fast_rcp(1.0f + __expf(-x)); }
__device__ __forceinline__ float tanh_f(float x) {
  x = fminf(15.0f, fmaxf(-15.0f, x));
  float e = __expf(2.0f * x);
  return (e - 1.0f) * fast_rcp(e + 1.0f);
}
__device__ __forceinline__ f16x8 cvt8(float4 a, float4 b) {
  f16x8 h;
  h[0] = (_Float16)a.x; h[1] = (_Float16)a.y; h[2] = (_Float16)a.z; h[3] = (_Float16)a.w;
  h[4] = (_Float16)b.x; h[5] = (_Float16)b.y; h[6] = (_Float16)b.z; h[7] = (_Float16)b.w;
  return h;
}

__global__ void transcode_f16(const float* __restrict__ Wih, const float* __restrict__ Whh,
                              _Float16* __restrict__ ws) {
  const int i4 = (blockIdx.x * 256 + threadIdx.x) * 4;
  if (i4 < WIH_ELEMS) {
    float4 v = *(const float4*)(Wih + i4);
    ws[i4] = (_Float16)v.x; ws[i4+1] = (_Float16)v.y; ws[i4+2] = (_Float16)v.z; ws[i4+3] = (_Float16)v.w;
  } else {
    const int j4 = i4 - WIH_ELEMS;
    float4 v = *(const float4*)(Whh + j4);
    _Float16* w2 = ws + WIH_ELEMS;
    w2[j4] = (_Float16)v.x; w2[j4+1] = (_Float16)v.y; w2[j4+2] = (_Float16)v.z; w2[j4+3] = (_Float16)v.w;
  }
}

// Fused LSTM, quarter-tile pipeline. Quarter q (0..31) = chunk q>>2, K-range (q&3)*128.
// Per q: loadB(q+1) regs -> MFMA[B(q), buf(q&1)] (compiler wait vmcnt(24), counted) ->
// vmcnt(16) retiring exactly DMA(q+1) -> barrier -> issueDMA(q+2) into buf(q&1) (safe:
// all waves past their reads). DMA(q+2)+B(q+1) remain in flight across phase B.
// x staged fp32 by global_load_lds (no staging VGPRs); fp32->fp16 cvt at fragment read.
// Both-sides XOR swizzle: source chunk c = (lane&31) ^ (row&7); read chunk G ^ (row&7).
__global__ __launch_bounds__(256, 2)
void lstm_fused(const float* __restrict__ x, const _Float16* __restrict__ ws,
                const float* __restrict__ bih, const float* __restrict__ bhh,
                const float* __restrict__ Wfc, const float* __restrict__ bfc,
                float* __restrict__ out)
{
  __shared__ __align__(16) float Abuf[2][64 * 128];   // 2 x 32KB quarter-tiles
  __shared__ __align__(16) _Float16 hbuf[2][8][72];
  __shared__ float cb[8][64];
  __shared__ float h32[8][64];

  const int tid  = threadIdx.x;
  const int wv   = tid >> 6;
  const int lane = tid & 63;
  const int ln   = lane & 15;
  const int kg   = lane >> 4;
  const int br0  = blockIdx.x * BR;
  const int u    = wv * 16 + ln;

  const _Float16* Wihh = ws;
  const _Float16* Whhh = ws + WIH_ELEMS;

  for (int i = tid; i < 2 * 8 * 72; i += 256) (&hbuf[0][0][0])[i] = (_Float16)0.0f;
  for (int i = tid; i < 8 * 64; i += 256) (&cb[0][0])[i] = 0.0f;

  // Whh fragments + bias: loaded BEFORE the drain so the counted stream starts clean.
  f16x8 whhf[4][2];
  #pragma unroll
  for (int g = 0; g < 4; ++g)
    #pragma unroll
    for (int k2 = 0; k2 < 2; ++k2)
      whhf[g][k2] = *(const f16x8*)(Whhh + (size_t)((g * 4 + wv) * 16 + ln) * H_SZ
                                         + kg * 8 + k2 * 32);
  float bsum[4];
  #pragma unroll
  for (int g = 0; g < 4; ++g) bsum[g] = bih[g * 64 + u] + bhh[g * 64 + u];

  __syncthreads();   // full drain; all VMEM after this point is hand-counted

  // DMA one quarter (8 instr/wave x 1KB). Dest linear: unit kk covers rows {2kk,2kk+1},
  // lane l -> row 2kk+(l>>5), phys chunk l&31. Source pre-swizzled: c = (l&31)^(row&7).
  auto issueDMA = [&](int qidx) {
    const int qt = qidx < 32 ? qidx : 31;     // tail dummy (never consumed)
    const int slot = qidx & 1;
    const int cc2 = qt >> 2, kq2 = qt & 3;
    #pragma unroll
    for (int i = 0; i < 8; ++i) {
      const int kk  = wv * 8 + i;
      const int row = 2 * kk + (lane >> 5);
      const int c   = (lane & 31) ^ (row & 7);
      const float* src = x + (size_t)(br0 + (row & 7)) * (T_SZ * F_SZ)
                           + (size_t)(cc2 * 8 + (row >> 3)) * F_SZ + kq2 * 128 + c * 4;
      __builtin_amdgcn_global_load_lds(src, &Abuf[slot][kk * 256], 16, 0, 0);
    }
  };
  // Full-quarter B fragments: [gate][K-step] f16x8, 16 x 16B loads (L2-hot fp16 Wih).
  auto loadB = [&](f16x8 (&b)[4][4], int kq) {
    #pragma unroll
    for (int g = 0; g < 4; ++g)
      #pragma unroll
      for (int j = 0; j < 4; ++j)
        b[g][j] = *(const f16x8*)(Wihh + (size_t)((g * 4 + wv) * 16 + ln) * F_SZ
                                       + kq * 128 + j * 32 + kg * 8);
  };

  f32x4 acc[4][4];
  auto mfmaQ = [&](const f16x8 (&b)[4][4], int slot) {
    const float* ab = &Abuf[slot][0];
    #pragma unroll
    for (int j = 0; j < 4; ++j)
      #pragma unroll
      for (int mt = 0; mt < 4; ++mt) {
        const int row = mt * 16 + ln;
        const int c0 = (j * 8 + kg * 2) ^ (ln & 7);
        const int c1 = (j * 8 + kg * 2 + 1) ^ (ln & 7);
        float4 a0 = *(const float4*)(ab + row * 128 + c0 * 4);
        float4 a1 = *(const float4*)(ab + row * 128 + c1 * 4);
        f16x8 af = cvt8(a0, a1);
        #pragma unroll
        for (int g = 0; g < 4; ++g)
          acc[mt][g] = __builtin_amdgcn_mfma_f32_16x16x32_f16(af, b[g][j], acc[mt][g], 0, 0, 0);
      }
  };

  f16x8 bA[4][4], bB[4][4];

  // Prologue: DMA(0), B(0), DMA(1) in queue; vmcnt(8) retires DMA(0)+B(0).
  issueDMA(0);
  loadB(bA, 0);
  issueDMA(1);
  __builtin_amdgcn_sched_barrier(0);
  asm volatile("s_waitcnt vmcnt(8)" ::: "memory");
  __builtin_amdgcn_s_barrier();
  __builtin_amdgcn_sched_barrier(0);

  for (int cc = 0; cc < 8; ++cc) {
    #pragma unroll
    for (int mt = 0; mt < 4; ++mt)
      #pragma unroll
      for (int g = 0; g < 4; ++g) acc[mt][g] = (f32x4){0.0f, 0.0f, 0.0f, 0.0f};

    // ---- Phase A: 4 quarters ----
    #pragma unroll
    for (int qq = 0; qq < 4; ++qq) {
      const int q = cc * 4 + qq;
      if (qq & 1) loadB(bA, (q + 1) & 3); else loadB(bB, (q + 1) & 3);
      __builtin_amdgcn_sched_barrier(0);
      mfmaQ((qq & 1) ? bB : bA, q & 1);
      __builtin_amdgcn_sched_barrier(0);
      asm volatile("s_waitcnt vmcnt(16)" ::: "memory");  // retire exactly DMA(q+1)
      __builtin_amdgcn_sched_barrier(0);
      __builtin_amdgcn_s_barrier();                      // buf(q&1) reads done, buf(q^1) ready
      __builtin_amdgcn_sched_barrier(0);
      issueDMA(q + 2);                                   // into buf(q&1): safe post-barrier
      __builtin_amdgcn_sched_barrier(0);
    }

    // ---- Phase B: 8 sequential steps (R8-verified); DMA/B stay in flight ----
    #pragma unroll
    for (int s = 0; s < 8; ++s) {
      const int st   = cc * 8 + s;
      const int half = s & 1;
      f16x8 ah0 = (f16x8){0, 0, 0, 0, 0, 0, 0, 0};
      f16x8 ah1 = (f16x8){0, 0, 0, 0, 0, 0, 0, 0};
      if ((ln >> 3) == half) {
        const _Float16* hr = &hbuf[st & 1][ln & 7][0];
        ah0 = *(const f16x8*)(hr + kg * 8);
        ah1 = *(const f16x8*)(hr + kg * 8 + 32);
      }
      f32x4 gf[4];
      #pragma unroll
      for (int g = 0; g < 4; ++g) {
        gf[g] = __builtin_amdgcn_mfma_f32_16x16x32_f16(ah0, whhf[g][0], acc[s >> 1][g], 0, 0, 0);
        gf[g] = __builtin_amdgcn_mfma_f32_16x16x32_f16(ah1, whhf[g][1], gf[g], 0, 0, 0);
      }
      if ((kg >> 1) == half) {
        const int b0 = (kg & 1) * 4;
        #pragma unroll
        for (int r = 0; r < 4; ++r) {
          const float iv = sigm(gf[0][r] + bsum[0]);
          const float fv = sigm(gf[1][r] + bsum[1]);
          const float gv = tanh_f(gf[2][r] + bsum[2]);
          const float ov = sigm(gf[3][r] + bsum[3]);
          const float cn = fv * cb[b0 + r][u] + iv * gv;
          cb[b0 + r][u] = cn;
          const float hn = ov * tanh_f(cn);
          hbuf[(st + 1) & 1][b0 + r][u] = (_Float16)hn;
          if (st == T_SZ - 1) h32[b0 + r][u] = hn;
        }
      }
      asm volatile("s_waitcnt lgkmcnt(0)" ::: "memory");
      __builtin_amdgcn_s_barrier();                      // raw: no vmcnt drain
      __builtin_amdgcn_sched_barrier(0);
    }
  }

  __syncthreads();   // drains tail dummies
  if (tid < 16) {
    const int r = tid >> 1, j = tid & 1;
    float a = bfc[j];
    #pragma unroll
    for (int uu = 0; uu < 64; ++uu) a += h32[r][uu] * Wfc[j * 64 + uu];
    out[(size_t)(br0 + r) * 2 + j] = a;
  }
}

extern "C" void kernel_launch(void* const* d_in, const int* in_sizes, int n_in,
                              void* d_out, int out_size, void* d_ws, size_t ws_size,
                              hipStream_t stream) {
  const float* x   = (const float*)d_in[0];
  const float* Wih = (const float*)d_in[1];
  const float* Whh = (const float*)d_in[2];
  const float* bih = (const float*)d_in[3];
  const float* bhh = (const float*)d_in[4];
  const float* Wfc = (const float*)d_in[5];
  const float* bfc = (const float*)d_in[6];
  float* out = (float*)d_out;
  _Float16* ws = (_Float16*)d_ws;   // 288 KB used

  transcode_f16<<<dim3(144), dim3(256), 0, stream>>>(Wih, Whh, ws);
  lstm_fused<<<dim3(B_SZ / BR), dim3(256), 0, stream>>>(x, ws, bih, bhh, Wfc, bfc, out);
}

// Round 10
// 295.578 us; speedup vs baseline: 1.0565x; 1.0565x over previous
//
#include <hip/hip_runtime.h>

#define B_SZ 4096
#define T_SZ 64
#define F_SZ 512
#define H_SZ 64
#define BR 4                    // 1024 blocks, 3 resident/CU
#define WIH_ELEMS (256 * 512)

typedef _Float16 f16x8 __attribute__((ext_vector_type(8)));
typedef float f32x4 __attribute__((ext_vector_type(4)));

__device__ __forceinline__ float fast_rcp(float x) { return __builtin_amdgcn_rcpf(x); }
__device__ __forceinline__ float sigm(float x) { return fast_rcp(1.0f + __expf(-x)); }
__device__ __forceinline__ float tanh_f(float x) {
  x = fminf(15.0f, fmaxf(-15.0f, x));
  float e = __expf(2.0f * x);
  return (e - 1.0f) * fast_rcp(e + 1.0f);
}
__device__ __forceinline__ f16x8 cvt8(float4 a, float4 b) {
  f16x8 h;
  h[0] = (_Float16)a.x; h[1] = (_Float16)a.y; h[2] = (_Float16)a.z; h[3] = (_Float16)a.w;
  h[4] = (_Float16)b.x; h[5] = (_Float16)b.y; h[6] = (_Float16)b.z; h[7] = (_Float16)b.w;
  return h;
}

__global__ void transcode_f16(const float* __restrict__ Wih, const float* __restrict__ Whh,
                              _Float16* __restrict__ ws) {
  const int i4 = (blockIdx.x * 256 + threadIdx.x) * 4;
  if (i4 < WIH_ELEMS) {
    float4 v = *(const float4*)(Wih + i4);
    ws[i4] = (_Float16)v.x; ws[i4+1] = (_Float16)v.y; ws[i4+2] = (_Float16)v.z; ws[i4+3] = (_Float16)v.w;
  } else {
    const int j4 = i4 - WIH_ELEMS;
    float4 v = *(const float4*)(Whh + j4);
    _Float16* w2 = ws + WIH_ELEMS;
    w2[j4] = (_Float16)v.x; w2[j4+1] = (_Float16)v.y; w2[j4+2] = (_Float16)v.z; w2[j4+3] = (_Float16)v.w;
  }
}

// Fused LSTM, minimal-register counted pipeline.
// Tile tau (0..31) = chunk tau>>3, k-slice (tau&7)*64; 16KB (64 m-rows x 64 k fp32,
// one 256B-contiguous segment per row), ring of 3. Per iteration per wave:
//   s_barrier -> loadB(kp)[8] -> issueD(tau+2)[4] -> vmcnt(12) -> consume
// vmcnt(12) retires exactly D(tau+1) (issued 1 full iteration earlier -> long landed);
// induction: tile tau was retired by iter tau-1's vmcnt(12) BEFORE this iter's barrier,
// so ds_reads are safe. Compiler's B-wait = vmcnt(4) keeps D(tau+2) in flight, incl.
// across phase B. Register state: acc 64 + bfr 32 + whhf 16 -> no spill at cap 170.
// Both-sides XOR swizzle on the 16B chunks (source-side + read-side, LDS linear).
__global__ __launch_bounds__(256, 3)
void lstm_fused(const float* __restrict__ x, const _Float16* __restrict__ ws,
                const float* __restrict__ bih, const float* __restrict__ bhh,
                const float* __restrict__ Wfc, const float* __restrict__ bfc,
                float* __restrict__ out)
{
  __shared__ __align__(16) float Ax[3][64 * 64];      // 48 KB ring
  __shared__ __align__(16) _Float16 hbuf[2][4][72];
  __shared__ float cb[4][64];
  __shared__ float h32[4][64];

  const int tid  = threadIdx.x;
  const int wv   = tid >> 6;
  const int lane = tid & 63;
  const int ln   = lane & 15;
  const int kg   = lane >> 4;
  const int br0  = blockIdx.x * BR;
  const int u    = wv * 16 + ln;

  const _Float16* Wihh = ws;
  const _Float16* Whhh = ws + WIH_ELEMS;

  for (int i = tid; i < 2 * 4 * 72; i += 256) (&hbuf[0][0][0])[i] = (_Float16)0.0f;
  for (int i = tid; i < 4 * 64; i += 256) (&cb[0][0])[i] = 0.0f;

  f16x8 whhf[4][2];
  #pragma unroll
  for (int g = 0; g < 4; ++g)
    #pragma unroll
    for (int k2 = 0; k2 < 2; ++k2)
      whhf[g][k2] = *(const f16x8*)(Whhh + (size_t)((g * 4 + wv) * 16 + ln) * H_SZ
                                         + kg * 8 + k2 * 32);
  float bsum[4];
  #pragma unroll
  for (int g = 0; g < 4; ++g) bsum[g] = bih[g * 64 + u] + bhh[g * 64 + u];

  __syncthreads();   // full drain before the counted stream

  // DMA one tile (16 instr x 1KB; wave wv -> instrs i = wv*4+j). Lane l lands at
  // row m = 4i+(l>>4), phys chunk l&15; source chunk = (l&15) ^ (m&7).
  const int rl = lane >> 4;    // row-in-group 0..3 == batch row
  const int lc = lane & 15;    // phys 16B chunk
  auto issueD = [&](int tau, int slot) {
    const int tt = tau < 32 ? tau : 31;        // tail dummy, never consumed
    const int c2 = tt >> 3, kq = tt & 7;
    #pragma unroll
    for (int j = 0; j < 4; ++j) {
      const int i  = wv * 4 + j;
      const int sc = lc ^ (((i & 1) << 2) + rl);   // (l&15) ^ (m&7)
      const float* src = x + (size_t)(br0 + rl) * (T_SZ * F_SZ)
                           + (size_t)(c2 * 16 + i) * F_SZ + kq * 64 + sc * 4;
      __builtin_amdgcn_global_load_lds(src, &Ax[slot][i * 256], 16, 0, 0);
    }
  };
  auto loadB = [&](f16x8 (&b)[4][2], int kq) {
    #pragma unroll
    for (int g = 0; g < 4; ++g)
      #pragma unroll
      for (int ks = 0; ks < 2; ++ks)
        b[g][ks] = *(const f16x8*)(Wihh + (size_t)((g * 4 + wv) * 16 + ln) * F_SZ
                                        + kq * 64 + ks * 32 + kg * 8);
  };

  f32x4 acc[4][4];
  auto consume = [&](const f16x8 (&b)[4][2], int slot) {
    const float* ab = &Ax[slot][0];
    #pragma unroll
    for (int ks = 0; ks < 2; ++ks)
      #pragma unroll
      for (int mt = 0; mt < 4; ++mt) {
        const float* rp = ab + (size_t)(mt * 16 + ln) * 64;
        const int c0 = (ks * 8 + kg * 2) ^ (ln & 7);
        float4 a0 = *(const float4*)(rp + c0 * 4);
        float4 a1 = *(const float4*)(rp + (c0 ^ 1) * 4);
        f16x8 af = cvt8(a0, a1);
        #pragma unroll
        for (int g = 0; g < 4; ++g)
          acc[mt][g] = __builtin_amdgcn_mfma_f32_16x16x32_f16(af, b[g][ks], acc[mt][g], 0, 0, 0);
      }
  };

  f16x8 bfr[4][2];
  int sl = 0;                       // slot holding tile tau
  issueD(0, 0);
  issueD(1, 1);

  for (int cc = 0; cc < 4; ++cc) {
    #pragma unroll
    for (int mt = 0; mt < 4; ++mt)
      #pragma unroll
      for (int g = 0; g < 4; ++g) acc[mt][g] = (f32x4){0.0f, 0.0f, 0.0f, 0.0f};

    // ---- Phase A: 8 tiles (K=512) ----
    #pragma unroll
    for (int kp = 0; kp < 8; ++kp) {
      const int tau = cc * 8 + kp;
      __builtin_amdgcn_s_barrier();            // tile tau retired (prev iter's vmcnt) + slot free
      __builtin_amdgcn_sched_barrier(0);
      loadB(bfr, kp);
      __builtin_amdgcn_sched_barrier(0);
      int isl = sl + 2; if (isl >= 3) isl -= 3;
      issueD(tau + 2, isl);
      __builtin_amdgcn_sched_barrier(0);
      asm volatile("s_waitcnt vmcnt(12)" ::: "memory");  // retires exactly D(tau+1)
      __builtin_amdgcn_sched_barrier(0);
      consume(bfr, sl);
      ++sl; if (sl == 3) sl = 0;
    }

    // ---- Phase B: 16 sequential steps; step s -> m-tile s>>2, lane-quarter s&3 ----
    #pragma unroll
    for (int s = 0; s < 16; ++s) {
      const int st = cc * 16 + s;
      const int mt = s >> 2, kq = s & 3;
      f16x8 ah0 = (f16x8){0, 0, 0, 0, 0, 0, 0, 0};
      f16x8 ah1 = (f16x8){0, 0, 0, 0, 0, 0, 0, 0};
      if ((ln >> 2) == kq) {                   // A rows kq*4 + (ln&3) carry h
        const _Float16* hr = &hbuf[st & 1][ln & 3][0];
        ah0 = *(const f16x8*)(hr + kg * 8);
        ah1 = *(const f16x8*)(hr + kg * 8 + 32);
      }
      #pragma unroll
      for (int g = 0; g < 4; ++g) {            // adds only into this step's C-rows
        acc[mt][g] = __builtin_amdgcn_mfma_f32_16x16x32_f16(ah0, whhf[g][0], acc[mt][g], 0, 0, 0);
        acc[mt][g] = __builtin_amdgcn_mfma_f32_16x16x32_f16(ah1, whhf[g][1], acc[mt][g], 0, 0, 0);
      }
      if (kg == kq) {                          // C rows kq*4 + r
        #pragma unroll
        for (int r = 0; r < 4; ++r) {
          const float iv = sigm(acc[mt][0][r] + bsum[0]);
          const float fv = sigm(acc[mt][1][r] + bsum[1]);
          const float gv = tanh_f(acc[mt][2][r] + bsum[2]);
          const float ov = sigm(acc[mt][3][r] + bsum[3]);
          const float cn = fv * cb[r][u] + iv * gv;
          cb[r][u] = cn;
          const float hn = ov * tanh_f(cn);
          hbuf[(st + 1) & 1][r][u] = (_Float16)hn;
          if (st == T_SZ - 1) h32[r][u] = hn;
        }
      }
      asm volatile("s_waitcnt lgkmcnt(0)" ::: "memory");
      __builtin_amdgcn_s_barrier();            // raw: DMA stays in flight
      __builtin_amdgcn_sched_barrier(0);
    }
  }

  __syncthreads();   // drains tail dummies
  if (tid < 8) {
    const int r = tid >> 1, j = tid & 1;
    float a = bfc[j];
    #pragma unroll
    for (int uu = 0; uu < 64; ++uu) a += h32[r][uu] * Wfc[j * 64 + uu];
    out[(size_t)(br0 + r) * 2 + j] = a;
  }
}

extern "C" void kernel_launch(void* const* d_in, const int* in_sizes, int n_in,
                              void* d_out, int out_size, void* d_ws, size_t ws_size,
                              hipStream_t stream) {
  const float* x   = (const float*)d_in[0];
  const float* Wih = (const float*)d_in[1];
  const float* Whh = (const float*)d_in[2];
  const float* bih = (const float*)d_in[3];
  const float* bhh = (const float*)d_in[4];
  const float* Wfc = (const float*)d_in[5];
  const float* bfc = (const float*)d_in[6];
  float* out = (float*)d_out;
  _Float16* ws = (_Float16*)d_ws;   // 288 KB used

  transcode_f16<<<dim3(144), dim3(256), 0, stream>>>(Wih, Whh, ws);
  lstm_fused<<<dim3(B_SZ / BR), dim3(256), 0, stream>>>(x, ws, bih, bhh, Wfc, bfc, out);
}

// Round 11
// 178.285 us; speedup vs baseline: 1.7515x; 1.6579x over previous
//
#include <hip/hip_runtime.h>

#define B_SZ 4096
#define T_SZ 64
#define F_SZ 512
#define H_SZ 64
#define BR 8                    // 512 blocks, 2 blocks/CU
#define WIH_ELEMS (256 * 512)

typedef _Float16 f16x4 __attribute__((ext_vector_type(4)));
typedef _Float16 f16x8 __attribute__((ext_vector_type(8)));
typedef float f32x4 __attribute__((ext_vector_type(4)));

__device__ __forceinline__ float fast_rcp(float x) { return __builtin_amdgcn_rcpf(x); }
__device__ __forceinline__ float sigm(float x) { return fast_rcp(1.0f + __expf(-x)); }
__device__ __forceinline__ float tanh_f(float x) {
  x = fminf(15.0f, fmaxf(-15.0f, x));
  float e = __expf(2.0f * x);
  return (e - 1.0f) * fast_rcp(e + 1.0f);
}

__global__ void transcode_f16(const float* __restrict__ Wih, const float* __restrict__ Whh,
                              _Float16* __restrict__ ws) {
  const int i4 = (blockIdx.x * 256 + threadIdx.x) * 4;
  if (i4 < WIH_ELEMS) {
    float4 v = *(const float4*)(Wih + i4);
    ws[i4] = (_Float16)v.x; ws[i4+1] = (_Float16)v.y; ws[i4+2] = (_Float16)v.z; ws[i4+3] = (_Float16)v.w;
  } else {
    const int j4 = i4 - WIH_ELEMS;
    float4 v = *(const float4*)(Whh + j4);
    _Float16* w2 = ws + WIH_ELEMS;
    w2[j4] = (_Float16)v.x; w2[j4+1] = (_Float16)v.y; w2[j4+2] = (_Float16)v.z; w2[j4+3] = (_Float16)v.w;
  }
}

// Fused LSTM with the scan software-pipelined INTO the streaming K-loop.
// Iteration tau (0..63): k-tile kk=tau&7 of chunk cc=tau>>3.
//   loadB(kk) -> x-prefetch(tau+1, 4x1KB coalesced) -> MFMA(tile tau) ->
//   scan step (tau-8) of the PREVIOUS chunk -> cvt+ds_write tile tau+1 -> lgkm -> barrier.
// Chunk gates hand off through xgb (LDS, fp16) at each kk==7 boundary. No iteration is
// ever without x-loads in flight; barriers are raw; all VMEM is compiler-tracked (B first,
// x second -> MFMA's B-wait is vmcnt(4), x keeps flying until the late cvt).
__global__ __launch_bounds__(256, 2)
void lstm_fused(const float* __restrict__ x, const _Float16* __restrict__ ws,
                const float* __restrict__ bih, const float* __restrict__ bhh,
                const float* __restrict__ Wfc, const float* __restrict__ bfc,
                float* __restrict__ out)
{
  __shared__ __align__(16) _Float16 Ast[2][64 * 64];   // 2 x 8KB fp16 k-tiles, granule-swizzled
  __shared__ __align__(16) _Float16 xgb[8][8][256];    // 32KB: [step][brow][u*4+g]
  __shared__ __align__(16) _Float16 hbuf[2][8][72];
  __shared__ float cb[8][64];
  __shared__ float h32[8][64];

  const int tid  = threadIdx.x;
  const int wv   = tid >> 6;
  const int lane = tid & 63;
  const int ln   = lane & 15;
  const int kg   = lane >> 4;
  const int br0  = blockIdx.x * BR;
  const int u    = wv * 16 + ln;

  const _Float16* Wihh = ws;
  const _Float16* Whhh = ws + WIH_ELEMS;

  for (int i = tid; i < 2 * 8 * 72; i += 256) (&hbuf[0][0][0])[i] = (_Float16)0.0f;
  for (int i = tid; i < 8 * 64; i += 256) (&cb[0][0])[i] = 0.0f;

  f16x8 whhf[4][2];
  #pragma unroll
  for (int g = 0; g < 4; ++g)
    #pragma unroll
    for (int k2 = 0; k2 < 2; ++k2)
      whhf[g][k2] = *(const f16x8*)(Whhh + (size_t)((g * 4 + wv) * 16 + ln) * H_SZ
                                         + kg * 8 + k2 * 32);
  float bsum[4];
  #pragma unroll
  for (int g = 0; g < 4; ++g) bsum[g] = bih[g * 64 + u] + bhh[g * 64 + u];

  // ---- x prefetch: 4 x 1KB fully-coalesced instrs; load j = rows wv*16+4j..+4 ----
  auto loadX = [&](float4 (&p)[4], int t2) {
    const int tt = t2 < 64 ? t2 : 63;          // tail clamp (written to dead buffer)
    const int c2 = tt >> 3, kq = tt & 7;
    #pragma unroll
    for (int j = 0; j < 4; ++j) {
      const int row = wv * 16 + 4 * j + (lane >> 4);
      const float* sp = x + (size_t)(br0 + (row & 7)) * (T_SZ * F_SZ)
                          + (size_t)(c2 * 8 + (row >> 3)) * F_SZ + kq * 64 + (lane & 15) * 4;
      p[j] = *(const float4*)sp;
    }
  };
  // cvt + swizzled LDS write: fp32 chunk c16 -> granule c16>>1 (phys ^= row&7), half c16&1
  auto stageW = [&](const float4 (&p)[4], int buf) {
    #pragma unroll
    for (int j = 0; j < 4; ++j) {
      const int row = wv * 16 + 4 * j + (lane >> 4);
      const int c16 = lane & 15;
      const int pg  = (c16 >> 1) ^ (row & 7);
      f16x4 h = {(_Float16)p[j].x, (_Float16)p[j].y, (_Float16)p[j].z, (_Float16)p[j].w};
      *(f16x4*)&Ast[buf][row * 64 + pg * 8 + (c16 & 1) * 4] = h;
    }
  };
  auto loadB = [&](f16x8 (&b)[4][2], int kq) {
    #pragma unroll
    for (int g = 0; g < 4; ++g)
      #pragma unroll
      for (int ks = 0; ks < 2; ++ks)
        b[g][ks] = *(const f16x8*)(Wihh + (size_t)((g * 4 + wv) * 16 + ln) * F_SZ
                                        + kq * 64 + ks * 32 + kg * 8);
  };

  f32x4 acc[4][4];
  auto consume = [&](const f16x8 (&b)[4][2], int buf) {
    #pragma unroll
    for (int ks = 0; ks < 2; ++ks)
      #pragma unroll
      for (int mt = 0; mt < 4; ++mt) {
        const int m    = mt * 16 + ln;
        const int phys = (ks * 4 + kg) ^ (ln & 7);
        f16x8 af = *(const f16x8*)&Ast[buf][m * 64 + phys * 8];
        #pragma unroll
        for (int g = 0; g < 4; ++g)
          acc[mt][g] = __builtin_amdgcn_mfma_f32_16x16x32_f16(af, b[g][ks], acc[mt][g], 0, 0, 0);
      }
  };

  // One scan step (R4-verified mapping); gates come from xgb instead of live acc.
  auto scanStep = [&](int st) {
    const int sl = st & 7, half = sl & 1;
    f16x8 ah0 = (f16x8){0, 0, 0, 0, 0, 0, 0, 0};
    f16x8 ah1 = (f16x8){0, 0, 0, 0, 0, 0, 0, 0};
    if ((ln >> 3) == half) {
      const _Float16* hr = &hbuf[st & 1][ln & 7][0];
      ah0 = *(const f16x8*)(hr + kg * 8);
      ah1 = *(const f16x8*)(hr + kg * 8 + 32);
    }
    const bool val = (kg >> 1) == half;
    f32x4 gf[4];
    if (val) {
      #pragma unroll
      for (int r = 0; r < 4; ++r) {
        f16x4 xv = *(const f16x4*)&xgb[sl][(kg & 1) * 4 + r][u * 4];
        gf[0][r] = (float)xv[0]; gf[1][r] = (float)xv[1];
        gf[2][r] = (float)xv[2]; gf[3][r] = (float)xv[3];
      }
    } else {
      #pragma unroll
      for (int g = 0; g < 4; ++g) gf[g] = (f32x4){0.0f, 0.0f, 0.0f, 0.0f};
    }
    #pragma unroll
    for (int g = 0; g < 4; ++g) {
      gf[g] = __builtin_amdgcn_mfma_f32_16x16x32_f16(ah0, whhf[g][0], gf[g], 0, 0, 0);
      gf[g] = __builtin_amdgcn_mfma_f32_16x16x32_f16(ah1, whhf[g][1], gf[g], 0, 0, 0);
    }
    if (val) {
      const int b0 = (kg & 1) * 4;
      #pragma unroll
      for (int r = 0; r < 4; ++r) {
        const float iv = sigm(gf[0][r] + bsum[0]);
        const float fv = sigm(gf[1][r] + bsum[1]);
        const float gv = tanh_f(gf[2][r] + bsum[2]);
        const float ov = sigm(gf[3][r] + bsum[3]);
        const float cn = fv * cb[b0 + r][u] + iv * gv;
        cb[b0 + r][u] = cn;
        const float hn = ov * tanh_f(cn);
        hbuf[(st + 1) & 1][b0 + r][u] = (_Float16)hn;
        if (st == T_SZ - 1) h32[b0 + r][u] = hn;
      }
    }
  };

  // Prologue: stage tile 0 into buffer 0.
  {
    float4 xp0[4];
    loadX(xp0, 0);
    stageW(xp0, 0);
  }
  __syncthreads();   // zeros + tile 0 visible; one full drain only here

  #pragma unroll
  for (int mt = 0; mt < 4; ++mt)
    #pragma unroll
    for (int g = 0; g < 4; ++g) acc[mt][g] = (f32x4){0.0f, 0.0f, 0.0f, 0.0f};

  f16x8 bfr[4][2];
  for (int tau = 0; tau < 64; ++tau) {
    const int kk = tau & 7;
    loadB(bfr, kk);                      // B first: MFMA's B-wait leaves x flying
    float4 xp[4];
    loadX(xp, tau + 1);
    __builtin_amdgcn_sched_barrier(0);
    consume(bfr, tau & 1);               // xg MFMA for chunk tau>>3
    if (tau >= 8) scanStep(tau - 8);     // one step of the previous chunk
    __builtin_amdgcn_sched_barrier(0);
    stageW(xp, (tau + 1) & 1);           // natural vmcnt: x had a full iteration to land
    asm volatile("s_waitcnt lgkmcnt(0)" ::: "memory");
    __builtin_amdgcn_s_barrier();        // raw: next tile ready, h/c visible

    if (kk == 7) {                       // chunk handoff: acc -> xgb (fp16), reset acc
      #pragma unroll
      for (int mt = 0; mt < 4; ++mt) {
        const int sl2  = mt * 2 + (kg >> 1);
        const int brow = (kg & 1) * 4;
        #pragma unroll
        for (int r = 0; r < 4; ++r) {
          f16x4 h4 = {(_Float16)acc[mt][0][r], (_Float16)acc[mt][1][r],
                      (_Float16)acc[mt][2][r], (_Float16)acc[mt][3][r]};
          *(f16x4*)&xgb[sl2][brow + r][u * 4] = h4;
        }
      }
      asm volatile("s_waitcnt lgkmcnt(0)" ::: "memory");
      __builtin_amdgcn_s_barrier();
      #pragma unroll
      for (int mt = 0; mt < 4; ++mt)
        #pragma unroll
        for (int g = 0; g < 4; ++g) acc[mt][g] = (f32x4){0.0f, 0.0f, 0.0f, 0.0f};
    }
  }

  // Epilogue: last chunk's 8 scan steps (no staging left).
  for (int s2 = 56; s2 < 64; ++s2) {
    scanStep(s2);
    asm volatile("s_waitcnt lgkmcnt(0)" ::: "memory");
    __builtin_amdgcn_s_barrier();
  }

  __syncthreads();
  if (tid < 16) {
    const int r = tid >> 1, j = tid & 1;
    float a = bfc[j];
    #pragma unroll
    for (int uu = 0; uu < 64; ++uu) a += h32[r][uu] * Wfc[j * 64 + uu];
    out[(size_t)(br0 + r) * 2 + j] = a;
  }
}

extern "C" void kernel_launch(void* const* d_in, const int* in_sizes, int n_in,
                              void* d_out, int out_size, void* d_ws, size_t ws_size,
                              hipStream_t stream) {
  const float* x   = (const float*)d_in[0];
  const float* Wih = (const float*)d_in[1];
  const float* Whh = (const float*)d_in[2];
  const float* bih = (const float*)d_in[3];
  const float* bhh = (const float*)d_in[4];
  const float* Wfc = (const float*)d_in[5];
  const float* bfc = (const float*)d_in[6];
  float* out = (float*)d_out;
  _Float16* ws = (_Float16*)d_ws;   // 272 KB used

  transcode_f16<<<dim3(144), dim3(256), 0, stream>>>(Wih, Whh, ws);
  lstm_fused<<<dim3(B_SZ / BR), dim3(256), 0, stream>>>(x, ws, bih, bhh, Wfc, bfc, out);
}

// Round 12
// 176.655 us; speedup vs baseline: 1.7676x; 1.0092x over previous
//
#include <hip/hip_runtime.h>

#define B_SZ 4096
#define T_SZ 64
#define F_SZ 512
#define H_SZ 64
#define BR 8                    // 512 blocks, 2 blocks/CU
#define WIH_ELEMS (256 * 512)

typedef _Float16 f16x4 __attribute__((ext_vector_type(4)));
typedef _Float16 f16x8 __attribute__((ext_vector_type(8)));
typedef float f32x4 __attribute__((ext_vector_type(4)));

__device__ __forceinline__ float fast_rcp(float x) { return __builtin_amdgcn_rcpf(x); }
__device__ __forceinline__ float sigm(float x) { return fast_rcp(1.0f + __expf(-x)); }
__device__ __forceinline__ float tanh_f(float x) {
  x = fminf(15.0f, fmaxf(-15.0f, x));
  float e = __expf(2.0f * x);
  return (e - 1.0f) * fast_rcp(e + 1.0f);
}

__global__ void transcode_f16(const float* __restrict__ Wih, const float* __restrict__ Whh,
                              _Float16* __restrict__ ws) {
  const int i4 = (blockIdx.x * 256 + threadIdx.x) * 4;
  if (i4 < WIH_ELEMS) {
    float4 v = *(const float4*)(Wih + i4);
    ws[i4] = (_Float16)v.x; ws[i4+1] = (_Float16)v.y; ws[i4+2] = (_Float16)v.z; ws[i4+3] = (_Float16)v.w;
  } else {
    const int j4 = i4 - WIH_ELEMS;
    float4 v = *(const float4*)(Whh + j4);
    _Float16* w2 = ws + WIH_ELEMS;
    w2[j4] = (_Float16)v.x; w2[j4+1] = (_Float16)v.y; w2[j4+2] = (_Float16)v.z; w2[j4+3] = (_Float16)v.w;
  }
}

// Fused LSTM: scan software-pipelined into the K-loop (R11) + 2-deep x prefetch.
// Iter tau: loadB(kk) -> loadX(DST, tau+2) -> MFMA(tile tau) [B-wait vmcnt(4): retires
// x(tau+1), issued a FULL iteration earlier; x(tau+2) stays in flight] -> scan step
// (tau-8) -> stageW(SRC = x(tau+1)) [no wait needed] -> lgkm -> raw barrier.
// The HBM queue never drains; every wait targets loads >= 1 iteration old.
__global__ __launch_bounds__(256, 2)
void lstm_fused(const float* __restrict__ x, const _Float16* __restrict__ ws,
                const float* __restrict__ bih, const float* __restrict__ bhh,
                const float* __restrict__ Wfc, const float* __restrict__ bfc,
                float* __restrict__ out)
{
  __shared__ __align__(16) _Float16 Ast[2][64 * 64];   // 2 x 8KB fp16 k-tiles, granule-swizzled
  __shared__ __align__(16) _Float16 xgb[8][8][256];    // 32KB: [step][brow][u*4+g]
  __shared__ __align__(16) _Float16 hbuf[2][8][72];
  __shared__ float cb[8][64];
  __shared__ float h32[8][64];

  const int tid  = threadIdx.x;
  const int wv   = tid >> 6;
  const int lane = tid & 63;
  const int ln   = lane & 15;
  const int kg   = lane >> 4;
  const int br0  = blockIdx.x * BR;
  const int u    = wv * 16 + ln;

  const _Float16* Wihh = ws;
  const _Float16* Whhh = ws + WIH_ELEMS;

  for (int i = tid; i < 2 * 8 * 72; i += 256) (&hbuf[0][0][0])[i] = (_Float16)0.0f;
  for (int i = tid; i < 8 * 64; i += 256) (&cb[0][0])[i] = 0.0f;

  f16x8 whhf[4][2];
  #pragma unroll
  for (int g = 0; g < 4; ++g)
    #pragma unroll
    for (int k2 = 0; k2 < 2; ++k2)
      whhf[g][k2] = *(const f16x8*)(Whhh + (size_t)((g * 4 + wv) * 16 + ln) * H_SZ
                                         + kg * 8 + k2 * 32);
  float bsum[4];
  #pragma unroll
  for (int g = 0; g < 4; ++g) bsum[g] = bih[g * 64 + u] + bhh[g * 64 + u];

  auto loadX = [&](float4 (&p)[4], int t2) {
    const int tt = t2 < 64 ? t2 : 63;          // tail clamp (dead-buffer writes)
    const int c2 = tt >> 3, kq = tt & 7;
    #pragma unroll
    for (int j = 0; j < 4; ++j) {
      const int row = wv * 16 + 4 * j + (lane >> 4);
      const float* sp = x + (size_t)(br0 + (row & 7)) * (T_SZ * F_SZ)
                          + (size_t)(c2 * 8 + (row >> 3)) * F_SZ + kq * 64 + (lane & 15) * 4;
      p[j] = *(const float4*)sp;
    }
  };
  auto stageW = [&](const float4 (&p)[4], int buf) {
    #pragma unroll
    for (int j = 0; j < 4; ++j) {
      const int row = wv * 16 + 4 * j + (lane >> 4);
      const int c16 = lane & 15;
      const int pg  = (c16 >> 1) ^ (row & 7);
      f16x4 h = {(_Float16)p[j].x, (_Float16)p[j].y, (_Float16)p[j].z, (_Float16)p[j].w};
      *(f16x4*)&Ast[buf][row * 64 + pg * 8 + (c16 & 1) * 4] = h;
    }
  };
  auto loadB = [&](f16x8 (&b)[4][2], int kq) {
    #pragma unroll
    for (int g = 0; g < 4; ++g)
      #pragma unroll
      for (int ks = 0; ks < 2; ++ks)
        b[g][ks] = *(const f16x8*)(Wihh + (size_t)((g * 4 + wv) * 16 + ln) * F_SZ
                                        + kq * 64 + ks * 32 + kg * 8);
  };

  f32x4 acc[4][4];
  auto consume = [&](const f16x8 (&b)[4][2], int buf) {
    #pragma unroll
    for (int ks = 0; ks < 2; ++ks)
      #pragma unroll
      for (int mt = 0; mt < 4; ++mt) {
        const int m    = mt * 16 + ln;
        const int phys = (ks * 4 + kg) ^ (ln & 7);
        f16x8 af = *(const f16x8*)&Ast[buf][m * 64 + phys * 8];
        #pragma unroll
        for (int g = 0; g < 4; ++g)
          acc[mt][g] = __builtin_amdgcn_mfma_f32_16x16x32_f16(af, b[g][ks], acc[mt][g], 0, 0, 0);
      }
  };

  auto scanStep = [&](int st) {
    const int sl = st & 7, half = sl & 1;
    f16x8 ah0 = (f16x8){0, 0, 0, 0, 0, 0, 0, 0};
    f16x8 ah1 = (f16x8){0, 0, 0, 0, 0, 0, 0, 0};
    if ((ln >> 3) == half) {
      const _Float16* hr = &hbuf[st & 1][ln & 7][0];
      ah0 = *(const f16x8*)(hr + kg * 8);
      ah1 = *(const f16x8*)(hr + kg * 8 + 32);
    }
    const bool val = (kg >> 1) == half;
    f32x4 gf[4];
    if (val) {
      #pragma unroll
      for (int r = 0; r < 4; ++r) {
        f16x4 xv = *(const f16x4*)&xgb[sl][(kg & 1) * 4 + r][u * 4];
        gf[0][r] = (float)xv[0]; gf[1][r] = (float)xv[1];
        gf[2][r] = (float)xv[2]; gf[3][r] = (float)xv[3];
      }
    } else {
      #pragma unroll
      for (int g = 0; g < 4; ++g) gf[g] = (f32x4){0.0f, 0.0f, 0.0f, 0.0f};
    }
    #pragma unroll
    for (int g = 0; g < 4; ++g) {
      gf[g] = __builtin_amdgcn_mfma_f32_16x16x32_f16(ah0, whhf[g][0], gf[g], 0, 0, 0);
      gf[g] = __builtin_amdgcn_mfma_f32_16x16x32_f16(ah1, whhf[g][1], gf[g], 0, 0, 0);
    }
    if (val) {
      const int b0 = (kg & 1) * 4;
      #pragma unroll
      for (int r = 0; r < 4; ++r) {
        const float iv = sigm(gf[0][r] + bsum[0]);
        const float fv = sigm(gf[1][r] + bsum[1]);
        const float gv = tanh_f(gf[2][r] + bsum[2]);
        const float ov = sigm(gf[3][r] + bsum[3]);
        const float cn = fv * cb[b0 + r][u] + iv * gv;
        cb[b0 + r][u] = cn;
        const float hn = ov * tanh_f(cn);
        hbuf[(st + 1) & 1][b0 + r][u] = (_Float16)hn;
        if (st == T_SZ - 1) h32[b0 + r][u] = hn;
      }
    }
  };

  // chunk handoff: acc -> xgb fp16, then reset acc
  auto handoff = [&]() {
    #pragma unroll
    for (int mt = 0; mt < 4; ++mt) {
      const int sl2  = mt * 2 + (kg >> 1);
      const int brow = (kg & 1) * 4;
      #pragma unroll
      for (int r = 0; r < 4; ++r) {
        f16x4 h4 = {(_Float16)acc[mt][0][r], (_Float16)acc[mt][1][r],
                    (_Float16)acc[mt][2][r], (_Float16)acc[mt][3][r]};
        *(f16x4*)&xgb[sl2][brow + r][u * 4] = h4;
      }
    }
    asm volatile("s_waitcnt lgkmcnt(0)" ::: "memory");
    __builtin_amdgcn_s_barrier();
    #pragma unroll
    for (int mt = 0; mt < 4; ++mt)
      #pragma unroll
      for (int g = 0; g < 4; ++g) acc[mt][g] = (f32x4){0.0f, 0.0f, 0.0f, 0.0f};
  };

  f16x8 bfr[4][2];
  float4 xpA[4], xpB[4];

// ITER(tau): SRC holds x(tau+1) (issued 1 iter ago), DST receives x(tau+2).
#define ITER(tau, SRC, DST)                                                  \
  do {                                                                       \
    const int kk_ = (tau) & 7;                                               \
    loadB(bfr, kk_);                                                         \
    loadX(DST, (tau) + 2);                                                   \
    __builtin_amdgcn_sched_barrier(0);                                       \
    consume(bfr, (tau) & 1);        /* B-wait vmcnt(4): retires x(tau+1) */  \
    if ((tau) >= 8) scanStep((tau) - 8);                                     \
    __builtin_amdgcn_sched_barrier(0);                                       \
    stageW(SRC, ((tau) + 1) & 1);   /* already retired: no wait */           \
    asm volatile("s_waitcnt lgkmcnt(0)" ::: "memory");                       \
    __builtin_amdgcn_s_barrier();                                            \
    if (kk_ == 7) handoff();                                                 \
  } while (0)

  // Prologue: stage tile 0; xpA <- x(1).
  loadX(xpA, 0);
  stageW(xpA, 0);
  loadX(xpA, 1);
  __syncthreads();   // zeros + tile 0 visible (one-time full drain)

  #pragma unroll
  for (int mt = 0; mt < 4; ++mt)
    #pragma unroll
    for (int g = 0; g < 4; ++g) acc[mt][g] = (f32x4){0.0f, 0.0f, 0.0f, 0.0f};

  for (int p = 0; p < 32; ++p) {
    ITER(2 * p,     xpA, xpB);
    ITER(2 * p + 1, xpB, xpA);
  }
#undef ITER

  // Epilogue: last chunk's 8 scan steps.
  for (int s2 = 56; s2 < 64; ++s2) {
    scanStep(s2);
    asm volatile("s_waitcnt lgkmcnt(0)" ::: "memory");
    __builtin_amdgcn_s_barrier();
  }

  __syncthreads();
  if (tid < 16) {
    const int r = tid >> 1, j = tid & 1;
    float a = bfc[j];
    #pragma unroll
    for (int uu = 0; uu < 64; ++uu) a += h32[r][uu] * Wfc[j * 64 + uu];
    out[(size_t)(br0 + r) * 2 + j] = a;
  }
}

extern "C" void kernel_launch(void* const* d_in, const int* in_sizes, int n_in,
                              void* d_out, int out_size, void* d_ws, size_t ws_size,
                              hipStream_t stream) {
  const float* x   = (const float*)d_in[0];
  const float* Wih = (const float*)d_in[1];
  const float* Whh = (const float*)d_in[2];
  const float* bih = (const float*)d_in[3];
  const float* bhh = (const float*)d_in[4];
  const float* Wfc = (const float*)d_in[5];
  const float* bfc = (const float*)d_in[6];
  float* out = (float*)d_out;
  _Float16* ws = (_Float16*)d_ws;   // 272 KB used

  transcode_f16<<<dim3(144), dim3(256), 0, stream>>>(Wih, Whh, ws);
  lstm_fused<<<dim3(B_SZ / BR), dim3(256), 0, stream>>>(x, ws, bih, bhh, Wfc, bfc, out);
}